// Round 10
// baseline (191.762 us; speedup 1.0000x reference)
//
#include <hip/hip_runtime.h>
#include <hip/hip_bf16.h>

typedef __attribute__((ext_vector_type(8))) short bf16x8;
typedef __attribute__((ext_vector_type(8))) unsigned short u16x8;
typedef __attribute__((ext_vector_type(16))) float f32x16;
typedef __attribute__((ext_vector_type(4))) unsigned int u32x4;

#define MFMA32(a, b, c) __builtin_amdgcn_mfma_f32_32x32x16_bf16(a, b, c, 0, 0, 0)

constexpr int NSEQ = 8192;
constexpr int NH   = 8;
constexpr int DIM  = 64;
constexpr int KVB  = 64;
constexpr int NT   = NSEQ / KVB;         // 128 tiles
constexpr int NTH  = NT / 2;             // 64 tiles per KV-half
constexpr int SLAB = KVB * DIM;          // 4096 ushorts = 8KB per tile slab
constexpr float SCL2 = 0.18033688011112042f;  // 0.125 * log2(e)

__device__ __forceinline__ unsigned cvt_pk(float lo, float hi) {
    unsigned r;
    asm("v_cvt_pk_bf16_f32 %0, %1, %2" : "=v"(r) : "v"(lo), "v"(hi));
    return r;
}
__device__ __forceinline__ float exp2f_fast(float x) {
    float r;
    asm("v_exp_f32 %0, %1" : "=v"(r) : "v"(x));
    return r;
}
__device__ __forceinline__ float max3f(float a, float b, float c) {
    float r;
    asm("v_max3_f32 %0, %1, %2, %3" : "=v"(r) : "v"(a), "v"(b), "v"(c));
    return r;
}
// safe ONLY with provably-distinct operands (distinct live values)
__device__ __forceinline__ void pl32swap(unsigned& a, unsigned& b) {
    asm("v_permlane32_swap_b32 %0, %1" : "+v"(a), "+v"(b));
}
// (fallback kernel only)
__device__ __forceinline__ int swz(int row, int col) {
    return row * 64 + ((((col >> 3) ^ row) & 7) << 3) + (col & 7);
}

// ============ prep: fp32 K/V -> bf16 slabs in FRAGMENT-READ order ============
// Slab = 8 wave-instructions x 64 lanes x 16B, linear:
//   K chunk(instr=kh*4+kd, lane): K[t*64 + kh*32 + (lane&31)][h][kd*16 + (lane>>5)*8 + 0..7]
//   V chunk(instr=vh*4+ks, lane): V[t*64 + ks*16 + (lane>>5)*8 + 0..7][h][vh*32 + (lane&31)]
__global__ __launch_bounds__(256, 4)
void prep_kernel(const float* __restrict__ Kg, const float* __restrict__ Vg,
                 unsigned short* __restrict__ Kws, unsigned short* __restrict__ Vws) {
    __shared__ float Vf[64][65];
    const int tid = threadIdx.x;
    const int bid = blockIdx.x;
    if (bid < 1024) {  // ---- K ----
        const int h = bid >> 7, t = bid & 127;
        unsigned short* dst = Kws + (size_t)bid * SLAB;
#pragma unroll
        for (int j = 0; j < 2; ++j) {
            const int m = tid * 2 + j;
            const int instr = m >> 6, ln = m & 63;
            const int kh = instr >> 2, kd = instr & 3;
            const int row = t * 64 + kh * 32 + (ln & 31);
            const int col = kd * 16 + (ln >> 5) * 8;
            const float* src = Kg + ((size_t)row * NH + h) * DIM + col;
            float4 a = ((const float4*)src)[0];
            float4 b = ((const float4*)src)[1];
            u32x4 w;
            w[0] = cvt_pk(a.x, a.y); w[1] = cvt_pk(a.z, a.w);
            w[2] = cvt_pk(b.x, b.y); w[3] = cvt_pk(b.z, b.w);
            *(u32x4*)(dst + m * 8) = w;
        }
    } else {           // ---- V: transpose via LDS ----
        const int hb = bid - 1024;
        const int h = hb >> 7, t = hb & 127;
        const int key = tid >> 2, dc = (tid & 3) * 16;
        const float* src = Vg + ((size_t)(t * 64 + key) * NH + h) * DIM + dc;
#pragma unroll
        for (int i = 0; i < 4; ++i) {
            float4 a = ((const float4*)src)[i];
            Vf[key][dc + i * 4 + 0] = a.x; Vf[key][dc + i * 4 + 1] = a.y;
            Vf[key][dc + i * 4 + 2] = a.z; Vf[key][dc + i * 4 + 3] = a.w;
        }
        __syncthreads();
        unsigned short* dst = Vws + (size_t)hb * SLAB;
#pragma unroll
        for (int j = 0; j < 2; ++j) {
            const int m = tid * 2 + j;
            const int instr = m >> 6, ln = m & 63;
            const int vh = instr >> 2, ks = instr & 3;
            const int d  = vh * 32 + (ln & 31);
            const int k0 = ks * 16 + (ln >> 5) * 8;
            u32x4 w;
            w[0] = cvt_pk(Vf[k0 + 0][d], Vf[k0 + 1][d]);
            w[1] = cvt_pk(Vf[k0 + 2][d], Vf[k0 + 3][d]);
            w[2] = cvt_pk(Vf[k0 + 4][d], Vf[k0 + 5][d]);
            w[3] = cvt_pk(Vf[k0 + 6][d], Vf[k0 + 7][d]);
            *(u32x4*)(dst + m * 8) = w;
        }
    }
}

// ---- softmax for one q-group over one 32-key subtile (scores in one f32x16) ----
template<int G>
__device__ __forceinline__ void group_sm(const f32x16& S, float m_run[2], float l_run[2],
                                         f32x16 oacc[2][2], bf16x8 FR[2]) {
    float pm  = max3f(max3f(S[0], S[1], S[2]), max3f(S[3], S[4], S[5]), max3f(S[6], S[7], S[8]));
    float pm2 = max3f(max3f(S[9], S[10], S[11]), max3f(S[12], S[13], S[14]), S[15]);
    pm = fmaxf(pm, pm2);
    pm = fmaxf(pm, __shfl_xor(pm, 32));   // pair lanes share a q-row
    if (__any(pm > m_run[G] + 8.f)) {     // defer-max (T13)
        float mnew = fmaxf(m_run[G], pm);
        float corr = exp2f_fast(m_run[G] - mnew);
        m_run[G] = mnew;
        l_run[G] *= corr;
#pragma unroll
        for (int i = 0; i < 16; ++i) { oacc[G][0][i] *= corr; oacc[G][1][i] *= corr; }
    }
    float p[16];
#pragma unroll
    for (int i = 0; i < 16; ++i) p[i] = exp2f_fast(S[i] - m_run[G]);
    float ts[8];
#pragma unroll
    for (int i = 0; i < 8; ++i) ts[i] = p[i] + p[i + 8];
#pragma unroll
    for (int i = 0; i < 4; ++i) ts[i] += ts[i + 4];
    l_run[G] += (ts[0] + ts[1]) + (ts[2] + ts[3]);
    unsigned A0 = cvt_pk(p[0], p[1]),  A1 = cvt_pk(p[2], p[3]);
    unsigned A2 = cvt_pk(p[4], p[5]),  A3 = cvt_pk(p[6], p[7]);
    unsigned A4 = cvt_pk(p[8], p[9]),  A5 = cvt_pk(p[10], p[11]);
    unsigned A6 = cvt_pk(p[12], p[13]), A7 = cvt_pk(p[14], p[15]);
    pl32swap(A0, A2); pl32swap(A1, A3);
    pl32swap(A4, A6); pl32swap(A5, A7);
    u32x4 f0; f0[0] = A0; f0[1] = A1; f0[2] = A2; f0[3] = A3;
    u32x4 f1; f1[0] = A4; f1[1] = A5; f1[2] = A6; f1[3] = A7;
    FR[0] = __builtin_bit_cast(bf16x8, f0);
    FR[1] = __builtin_bit_cast(bf16x8, f1);
}

// ---- QK for one 32-key subtile (KB = 0/1), both q-groups ----
__device__ __forceinline__ void qk_sub(const unsigned short* Kbase, int KB, int fragoff,
                                       const bf16x8 qf[2][4], const f32x16& ZERO,
                                       f32x16& D0, f32x16& D1) {
    __builtin_amdgcn_s_setprio(1);
    bf16x8 kk = *(const bf16x8*)(Kbase + (KB * 4 + 0) * 512 + fragoff);
    D0 = MFMA32(kk, qf[0][0], ZERO);
    D1 = MFMA32(kk, qf[1][0], ZERO);
#pragma unroll
    for (int kd = 1; kd < 4; ++kd) {
        kk = *(const bf16x8*)(Kbase + (KB * 4 + kd) * 512 + fragoff);
        D0 = MFMA32(kk, qf[0][kd], D0);
        D1 = MFMA32(kk, qf[1][kd], D1);
    }
    __builtin_amdgcn_s_setprio(0);
}

// ---- PV for one 32-key subtile, both q-groups share V fragments ----
__device__ __forceinline__ void pv_sub(const unsigned short* Vbase, int KB, int fragoff,
                                       const bf16x8 fr0[2], const bf16x8 fr1[2],
                                       f32x16 oacc[2][2]) {
    __builtin_amdgcn_s_setprio(1);
#pragma unroll
    for (int ks2 = 0; ks2 < 2; ++ks2) {
        const int ksg = KB * 2 + ks2;
        bf16x8 vf0 = *(const bf16x8*)(Vbase + ksg * 512 + fragoff);
        bf16x8 vf1 = *(const bf16x8*)(Vbase + (4 + ksg) * 512 + fragoff);
        oacc[0][0] = MFMA32(vf0, fr0[ks2], oacc[0][0]);
        oacc[0][1] = MFMA32(vf1, fr0[ks2], oacc[0][1]);
        oacc[1][0] = MFMA32(vf0, fr1[ks2], oacc[1][0]);
        oacc[1][1] = MFMA32(vf1, fr1[ks2], oacc[1][1]);
    }
    __builtin_amdgcn_s_setprio(0);
}

// ============ main: subtile-pipelined, 4 waves = 2 KV-halves x 2 q-waves x 64 rows ============
__global__ __launch_bounds__(256, 2)
void fa_kernel(const float* __restrict__ Qg, const unsigned short* __restrict__ Kws,
               const unsigned short* __restrict__ Vws, float* __restrict__ Og) {
    __shared__ unsigned short KVb[2][2][2][SLAB];  // [K/V][half][dbuf][slab] = 64KB
    __shared__ float mrgML[2][2][128];             // [grp][m/l][row]

    const int tid  = threadIdx.x;
    const int lane = tid & 63;
    const int wave = tid >> 6;       // 0..3
    const int half_f = wave >> 1;    // KV-half
    const int qv_f   = wave & 1;     // q-wave within half (64 rows)
    const int la31 = lane & 31;
    const int hi   = lane >> 5;
    const int halftid = tid & 127;   // 2 waves per half stage the slab
    const int head  = blockIdx.x & 7;    // head pinned per XCD
    const int qtile = blockIdx.x >> 3;
    const int qbase = qtile * 128 + qv_f * 64;
    const int fragoff = lane * 8;

    // ---- persistent Q fragments, 2 groups x 32 rows ----
    bf16x8 qf[2][4];
#pragma unroll
    for (int g = 0; g < 2; ++g)
#pragma unroll
        for (int kd = 0; kd < 4; ++kd) {
            const float* qp = Qg + ((size_t)(qbase + g * 32 + la31) * NH + head) * DIM + kd * 16 + hi * 8;
            float4 a = ((const float4*)qp)[0];
            float4 b = ((const float4*)qp)[1];
            u32x4 w;
            w[0] = cvt_pk(a.x * SCL2, a.y * SCL2);
            w[1] = cvt_pk(a.z * SCL2, a.w * SCL2);
            w[2] = cvt_pk(b.x * SCL2, b.y * SCL2);
            w[3] = cvt_pk(b.z * SCL2, b.w * SCL2);
            qf[g][kd] = __builtin_bit_cast(bf16x8, w);
        }

    const unsigned short* ksl = Kws + ((size_t)head * NT + (size_t)half_f * NTH) * SLAB + halftid * 8;
    const unsigned short* vsl = Vws + ((size_t)head * NT + (size_t)half_f * NTH) * SLAB + halftid * 8;

    f32x16 oacc[2][2];
    const f32x16 ZERO = {0.f,0.f,0.f,0.f,0.f,0.f,0.f,0.f,0.f,0.f,0.f,0.f,0.f,0.f,0.f,0.f};
#pragma unroll
    for (int g = 0; g < 2; ++g)
#pragma unroll
        for (int nt = 0; nt < 2; ++nt) oacc[g][nt] = ZERO;
    float m_run[2] = {-1e30f, -1e30f}, l_run[2] = {0.f, 0.f};

    // ---- prologue: tile0 regs -> LDS[0]; issue tile1 loads; QK(subtile 0) ----
    u16x8 kr0 = *(const u16x8*)ksl,          kr1 = *(const u16x8*)(ksl + 1024);
    u16x8 kr2 = *(const u16x8*)(ksl + 2048), kr3 = *(const u16x8*)(ksl + 3072);
    u16x8 vr0 = *(const u16x8*)vsl,          vr1 = *(const u16x8*)(vsl + 1024);
    u16x8 vr2 = *(const u16x8*)(vsl + 2048), vr3 = *(const u16x8*)(vsl + 3072);
    ksl += SLAB; vsl += SLAB;
    {
        unsigned short* kw = &KVb[0][half_f][0][0];
        unsigned short* vw = &KVb[1][half_f][0][0];
        *(u16x8*)(kw + halftid * 8)        = kr0;
        *(u16x8*)(kw + 1024 + halftid * 8) = kr1;
        *(u16x8*)(kw + 2048 + halftid * 8) = kr2;
        *(u16x8*)(kw + 3072 + halftid * 8) = kr3;
        *(u16x8*)(vw + halftid * 8)        = vr0;
        *(u16x8*)(vw + 1024 + halftid * 8) = vr1;
        *(u16x8*)(vw + 2048 + halftid * 8) = vr2;
        *(u16x8*)(vw + 3072 + halftid * 8) = vr3;
    }
    __syncthreads();
    // issue tile1 loads
    kr0 = *(const u16x8*)ksl;          kr1 = *(const u16x8*)(ksl + 1024);
    kr2 = *(const u16x8*)(ksl + 2048); kr3 = *(const u16x8*)(ksl + 3072);
    vr0 = *(const u16x8*)vsl;          vr1 = *(const u16x8*)(vsl + 1024);
    vr2 = *(const u16x8*)(vsl + 2048); vr3 = *(const u16x8*)(vsl + 3072);
    ksl += SLAB; vsl += SLAB;

    f32x16 sA0, sA1, sB0, sB1;
    qk_sub(&KVb[0][half_f][0][0], 0, fragoff, qf, ZERO, sA0, sA1);

    for (int t = 0; t < NTH; ++t) {
        const int cur = t & 1, nxt = cur ^ 1;
        const unsigned short* Kcur = &KVb[0][half_f][cur][0];
        const unsigned short* Knxt = &KVb[0][half_f][nxt][0];
        const unsigned short* Vcur = &KVb[1][half_f][cur][0];

        __syncthreads();   // all waves done reading LDS[nxt] (tile t-1 PV)
        {
            unsigned short* kw = &KVb[0][half_f][nxt][0];
            unsigned short* vw = &KVb[1][half_f][nxt][0];
            *(u16x8*)(kw + halftid * 8)        = kr0;
            *(u16x8*)(kw + 1024 + halftid * 8) = kr1;
            *(u16x8*)(kw + 2048 + halftid * 8) = kr2;
            *(u16x8*)(kw + 3072 + halftid * 8) = kr3;
            *(u16x8*)(vw + halftid * 8)        = vr0;
            *(u16x8*)(vw + 1024 + halftid * 8) = vr1;
            *(u16x8*)(vw + 2048 + halftid * 8) = vr2;
            *(u16x8*)(vw + 3072 + halftid * 8) = vr3;
        }
        __syncthreads();   // LDS[nxt] (tile t+1) ready
        // issue loads for tile t+2 (pointer clamped: last slab re-read harmlessly)
        kr0 = *(const u16x8*)ksl;          kr1 = *(const u16x8*)(ksl + 1024);
        kr2 = *(const u16x8*)(ksl + 2048); kr3 = *(const u16x8*)(ksl + 3072);
        vr0 = *(const u16x8*)vsl;          vr1 = *(const u16x8*)(vsl + 1024);
        vr2 = *(const u16x8*)(vsl + 2048); vr3 = *(const u16x8*)(vsl + 3072);
        {
            const size_t adv = (t + 3 < NTH) ? (size_t)SLAB : 0;
            ksl += adv; vsl += adv;
        }

        // ---- phase A: QK(subtile 2t+1) || softmax(2t); PV(2t) ----
        qk_sub(Kcur, 1, fragoff, qf, ZERO, sB0, sB1);
        {
            bf16x8 fr0[2], fr1[2];
            group_sm<0>(sA0, m_run, l_run, oacc, fr0);
            group_sm<1>(sA1, m_run, l_run, oacc, fr1);
            pv_sub(Vcur, 0, fragoff, fr0, fr1, oacc);
        }
        // ---- phase B: QK(subtile 2t+2, tile t+1) || softmax(2t+1); PV(2t+1) ----
        qk_sub(Knxt, 0, fragoff, qf, ZERO, sA0, sA1);   // last iter: garbage, unused
        {
            bf16x8 fr0[2], fr1[2];
            group_sm<0>(sB0, m_run, l_run, oacc, fr0);
            group_sm<1>(sB1, m_run, l_run, oacc, fr1);
            pv_sub(Vcur, 1, fragoff, fr0, fr1, oacc);
        }
    }

    // ---- merge the two KV-halves (max-aware); mrgO reuses KV LDS ----
    __syncthreads();
    float* mrgO = (float*)&KVb[0][0][0][0];
    const int row0 = qv_f * 64;
    if (half_f) {
#pragma unroll
        for (int g = 0; g < 2; ++g) {
            const int row = row0 + g * 32 + la31;
#pragma unroll
            for (int nt = 0; nt < 2; ++nt)
#pragma unroll
                for (int i = 0; i < 16; ++i)
                    mrgO[hi * 4096 + (nt * 16 + i) * 128 + row] = oacc[g][nt][i];
            mrgML[g][0][qv_f * 64 + lane] = m_run[g];
            mrgML[g][1][qv_f * 64 + lane] = l_run[g];
        }
    }
    __syncthreads();
    if (!half_f) {
#pragma unroll
        for (int g = 0; g < 2; ++g) {
            const int row = row0 + g * 32 + la31;
            const float m1 = mrgML[g][0][qv_f * 64 + lane];
            const float l1 = mrgML[g][1][qv_f * 64 + lane];
            const float mnew = fmaxf(m_run[g], m1);
            const float c0 = exp2f_fast(m_run[g] - mnew);
            const float c1 = exp2f_fast(m1 - mnew);
            float lt = l_run[g] * c0 + l1 * c1;
#pragma unroll
            for (int nt = 0; nt < 2; ++nt)
#pragma unroll
                for (int i = 0; i < 16; ++i)
                    oacc[g][nt][i] = oacc[g][nt][i] * c0 + mrgO[hi * 4096 + (nt * 16 + i) * 128 + row] * c1;
            const float l_tot = lt + __shfl_xor(lt, 32);
            const float inv = __builtin_amdgcn_rcpf(l_tot);
            float* obase = Og + ((size_t)(qtile * 128 + row) * NH + head) * DIM;
#pragma unroll
            for (int nt = 0; nt < 2; ++nt)
#pragma unroll
                for (int rq = 0; rq < 4; ++rq) {
                    float4 o;
                    o.x = oacc[g][nt][rq * 4 + 0] * inv;
                    o.y = oacc[g][nt][rq * 4 + 1] * inv;
                    o.z = oacc[g][nt][rq * 4 + 2] * inv;
                    o.w = oacc[g][nt][rq * 4 + 3] * inv;
                    *(float4*)(obase + nt * 32 + rq * 8 + hi * 4) = o;
                }
        }
    }
}

// ============ fallback (round-4 proven kernel) if ws too small ============
__global__ __launch_bounds__(256, 2)
void fb_kernel(const float* __restrict__ Qg, const float* __restrict__ Kg,
               const float* __restrict__ Vg, float* __restrict__ Og) {
    __shared__ unsigned short Kl[KVB][DIM];
    __shared__ unsigned short Vt[DIM][KVB];
    unsigned short* Kbase = &Kl[0][0];
    unsigned short* Vbase = &Vt[0][0];
    const int tid  = threadIdx.x;
    const int lane = tid & 63;
    const int wave = tid >> 6;
    const int la31 = lane & 31;
    const int hi   = lane >> 5;
    const int head  = blockIdx.x & 7;
    const int qtile = blockIdx.x >> 3;
    const int q     = qtile * 128 + wave * 32 + la31;
    bf16x8 qf[4];
#pragma unroll
    for (int kd = 0; kd < 4; ++kd) {
        const float* qp = Qg + ((size_t)q * NH + head) * DIM + kd * 16 + hi * 8;
        float4 a = ((const float4*)qp)[0];
        float4 b = ((const float4*)qp)[1];
        u32x4 w;
        w[0] = cvt_pk(a.x * SCL2, a.y * SCL2);
        w[1] = cvt_pk(a.z * SCL2, a.w * SCL2);
        w[2] = cvt_pk(b.x * SCL2, b.y * SCL2);
        w[3] = cvt_pk(b.z * SCL2, b.w * SCL2);
        qf[kd] = __builtin_bit_cast(bf16x8, w);
    }
    const int ksrow = tid & 63;
    const int kscol = (tid >> 6) * 16;
    const int vpair = tid & 31;
    const int vcg   = tid >> 5;
    const float* kptr  = Kg + ((size_t)ksrow * NH + head) * DIM + kscol;
    const float* vptr0 = Vg + ((size_t)(2 * vpair) * NH + head) * DIM + vcg * 8;
    const float* vptr1 = vptr0 + NH * DIM;
    constexpr size_t STRIDE = (size_t)KVB * NH * DIM;
    const int kIdx0 = swz(ksrow, kscol);
    const int kIdx1 = swz(ksrow, kscol + 8);
    f32x16 oacc[2];
#pragma unroll
    for (int nt = 0; nt < 2; ++nt)
#pragma unroll
        for (int i = 0; i < 16; ++i) oacc[nt][i] = 0.f;
    float m_run = -1e30f, l_run = 0.f;
    float4 kr0 = ((const float4*)kptr)[0], kr1 = ((const float4*)kptr)[1];
    float4 kr2 = ((const float4*)kptr)[2], kr3 = ((const float4*)kptr)[3];
    float4 va0 = ((const float4*)vptr0)[0], va1 = ((const float4*)vptr0)[1];
    float4 vb0 = ((const float4*)vptr1)[0], vb1 = ((const float4*)vptr1)[1];
    kptr += STRIDE; vptr0 += STRIDE; vptr1 += STRIDE;
    for (int t = 0; t < NT; ++t) {
        __syncthreads();
        {
            u32x4 w;
            w[0] = cvt_pk(kr0.x, kr0.y); w[1] = cvt_pk(kr0.z, kr0.w);
            w[2] = cvt_pk(kr1.x, kr1.y); w[3] = cvt_pk(kr1.z, kr1.w);
            *(u32x4*)(Kbase + kIdx0) = w;
            w[0] = cvt_pk(kr2.x, kr2.y); w[1] = cvt_pk(kr2.z, kr2.w);
            w[2] = cvt_pk(kr3.x, kr3.y); w[3] = cvt_pk(kr3.z, kr3.w);
            *(u32x4*)(Kbase + kIdx1) = w;
        }
        {
            *(unsigned*)(Vbase + swz(vcg * 8 + 0, 2 * vpair)) = cvt_pk(va0.x, vb0.x);
            *(unsigned*)(Vbase + swz(vcg * 8 + 1, 2 * vpair)) = cvt_pk(va0.y, vb0.y);
            *(unsigned*)(Vbase + swz(vcg * 8 + 2, 2 * vpair)) = cvt_pk(va0.z, vb0.z);
            *(unsigned*)(Vbase + swz(vcg * 8 + 3, 2 * vpair)) = cvt_pk(va0.w, vb0.w);
            *(unsigned*)(Vbase + swz(vcg * 8 + 4, 2 * vpair)) = cvt_pk(va1.x, vb1.x);
            *(unsigned*)(Vbase + swz(vcg * 8 + 5, 2 * vpair)) = cvt_pk(va1.y, vb1.y);
            *(unsigned*)(Vbase + swz(vcg * 8 + 6, 2 * vpair)) = cvt_pk(va1.z, vb1.z);
            *(unsigned*)(Vbase + swz(vcg * 8 + 7, 2 * vpair)) = cvt_pk(va1.w, vb1.w);
        }
        __syncthreads();
        if (t + 1 < NT) {
            kr0 = ((const float4*)kptr)[0]; kr1 = ((const float4*)kptr)[1];
            kr2 = ((const float4*)kptr)[2]; kr3 = ((const float4*)kptr)[3];
            va0 = ((const float4*)vptr0)[0]; va1 = ((const float4*)vptr0)[1];
            vb0 = ((const float4*)vptr1)[0]; vb1 = ((const float4*)vptr1)[1];
            kptr += STRIDE; vptr0 += STRIDE; vptr1 += STRIDE;
        }
        f32x16 s0, s1;
#pragma unroll
        for (int i = 0; i < 16; ++i) { s0[i] = 0.f; s1[i] = 0.f; }
        __builtin_amdgcn_s_setprio(1);
#pragma unroll
        for (int kd = 0; kd < 4; ++kd) {
            bf16x8 k0 = *(const bf16x8*)(Kbase + swz(la31, kd * 16 + hi * 8));
            bf16x8 k1 = *(const bf16x8*)(Kbase + swz(32 + la31, kd * 16 + hi * 8));
            s0 = MFMA32(k0, qf[kd], s0);
            s1 = MFMA32(k1, qf[kd], s1);
        }
        __builtin_amdgcn_s_setprio(0);
        float pmv[16];
#pragma unroll
        for (int i = 0; i < 16; ++i) pmv[i] = fmaxf(s0[i], s1[i]);
#pragma unroll
        for (int st = 8; st >= 1; st >>= 1)
#pragma unroll
            for (int i = 0; i < 8; ++i)
                if (i < st) pmv[i] = fmaxf(pmv[i], pmv[i + st]);
        float pm = pmv[0];
        pm = fmaxf(pm, __shfl_xor(pm, 32));
        if (__any(pm > m_run + 8.f)) {
            float mnew = fmaxf(m_run, pm);
            float corr = exp2f_fast(m_run - mnew);
            m_run = mnew;
            l_run *= corr;
#pragma unroll
            for (int i = 0; i < 16; ++i) { oacc[0][i] *= corr; oacc[1][i] *= corr; }
        }
#pragma unroll
        for (int kb = 0; kb < 2; ++kb) {
            const f32x16& s = kb ? s1 : s0;
            float p[16];
#pragma unroll
            for (int i = 0; i < 16; ++i) p[i] = exp2f_fast(s[i] - m_run);
            float ts[8];
#pragma unroll
            for (int i = 0; i < 8; ++i) ts[i] = p[i] + p[i + 8];
#pragma unroll
            for (int i = 0; i < 4; ++i) ts[i] += ts[i + 4];
            l_run += (ts[0] + ts[1]) + (ts[2] + ts[3]);
            unsigned A[8];
#pragma unroll
            for (int j = 0; j < 8; ++j) A[j] = cvt_pk(p[2 * j], p[2 * j + 1]);
            pl32swap(A[0], A[2]); pl32swap(A[1], A[3]);
            pl32swap(A[4], A[6]); pl32swap(A[5], A[7]);
            u32x4 f0v; f0v[0] = A[0]; f0v[1] = A[1]; f0v[2] = A[2]; f0v[3] = A[3];
            u32x4 f1v; f1v[0] = A[4]; f1v[1] = A[5]; f1v[2] = A[6]; f1v[3] = A[7];
            bf16x8 frag[2] = { __builtin_bit_cast(bf16x8, f0v), __builtin_bit_cast(bf16x8, f1v) };
            __builtin_amdgcn_s_setprio(1);
#pragma unroll
            for (int ksl = 0; ksl < 2; ++ksl) {
                const int ksg = kb * 2 + ksl;
                bf16x8 vf0 = *(const bf16x8*)(Vbase + swz(la31, ksg * 16 + hi * 8));
                bf16x8 vf1 = *(const bf16x8*)(Vbase + swz(32 + la31, ksg * 16 + hi * 8));
                oacc[0] = MFMA32(vf0, frag[ksl], oacc[0]);
                oacc[1] = MFMA32(vf1, frag[ksl], oacc[1]);
            }
            __builtin_amdgcn_s_setprio(0);
        }
    }
    {
        float l_tot = l_run + __shfl_xor(l_run, 32);
        float inv = __builtin_amdgcn_rcpf(l_tot);
        float* obase = Og + ((size_t)q * NH + head) * DIM;
#pragma unroll
        for (int nt = 0; nt < 2; ++nt)
#pragma unroll
            for (int rq = 0; rq < 4; ++rq) {
                float4 o;
                o.x = oacc[nt][rq * 4 + 0] * inv;
                o.y = oacc[nt][rq * 4 + 1] * inv;
                o.z = oacc[nt][rq * 4 + 2] * inv;
                o.w = oacc[nt][rq * 4 + 3] * inv;
                *(float4*)(obase + nt * 32 + rq * 8 + hi * 4) = o;
            }
    }
}

extern "C" void kernel_launch(void* const* d_in, const int* in_sizes, int n_in,
                              void* d_out, int out_size, void* d_ws, size_t ws_size,
                              hipStream_t stream) {
    const float* q = (const float*)d_in[0];
    const float* k = (const float*)d_in[1];
    const float* v = (const float*)d_in[2];
    float* out = (float*)d_out;
    constexpr size_t KV_WS = 2ull * NH * NT * SLAB * sizeof(unsigned short);  // 16.78 MB
    if (ws_size >= KV_WS) {
        unsigned short* Kws = (unsigned short*)d_ws;
        unsigned short* Vws = Kws + (size_t)NH * NT * SLAB;
        hipLaunchKernelGGL(prep_kernel, dim3(2048), dim3(256), 0, stream, k, v, Kws, Vws);
        hipLaunchKernelGGL(fa_kernel, dim3(512), dim3(256), 0, stream, q, Kws, Vws, out);
    } else {
        hipLaunchKernelGGL(fb_kernel, dim3(512), dim3(256), 0, stream, q, k, v, out);
    }
}

// Round 11
// 187.589 us; speedup vs baseline: 1.0222x; 1.0222x over previous
//
#include <hip/hip_runtime.h>
#include <hip/hip_bf16.h>

typedef __attribute__((ext_vector_type(8))) short bf16x8;
typedef __attribute__((ext_vector_type(8))) unsigned short u16x8;
typedef __attribute__((ext_vector_type(16))) float f32x16;
typedef __attribute__((ext_vector_type(4))) unsigned int u32x4;

#define MFMA32(a, b, c) __builtin_amdgcn_mfma_f32_32x32x16_bf16(a, b, c, 0, 0, 0)

constexpr int NSEQ = 8192;
constexpr int NH   = 8;
constexpr int DIM  = 64;
constexpr int KVB  = 64;
constexpr int NT   = NSEQ / KVB;         // 128 tiles
constexpr int NTH  = NT / 2;             // 64 tiles per KV-half
constexpr int SLAB = KVB * DIM;          // 4096 ushorts = 8KB per tile slab
constexpr float SCL2 = 0.18033688011112042f;  // 0.125 * log2(e)

__device__ __forceinline__ unsigned cvt_pk(float lo, float hi) {
    unsigned r;
    asm("v_cvt_pk_bf16_f32 %0, %1, %2" : "=v"(r) : "v"(lo), "v"(hi));
    return r;
}
__device__ __forceinline__ float exp2f_fast(float x) {
    float r;
    asm("v_exp_f32 %0, %1" : "=v"(r) : "v"(x));
    return r;
}
__device__ __forceinline__ float max3f(float a, float b, float c) {
    float r;
    asm("v_max3_f32 %0, %1, %2, %3" : "=v"(r) : "v"(a), "v"(b), "v"(c));
    return r;
}
// safe ONLY with provably-distinct operands (distinct live values)
__device__ __forceinline__ void pl32swap(unsigned& a, unsigned& b) {
    asm("v_permlane32_swap_b32 %0, %1" : "+v"(a), "+v"(b));
}
// (fallback kernel only)
__device__ __forceinline__ int swz(int row, int col) {
    return row * 64 + ((((col >> 3) ^ row) & 7) << 3) + (col & 7);
}

// ============ prep: fp32 K/V -> bf16 slabs in FRAGMENT-READ order ============
// Slab = 8 wave-instructions x 64 lanes x 16B, linear:
//   K chunk(instr=kh*4+kd, lane): K[t*64 + kh*32 + (lane&31)][h][kd*16 + (lane>>5)*8 + 0..7]
//   V chunk(instr=vh*4+ks, lane): V[t*64 + ks*16 + (lane>>5)*8 + 0..7][h][vh*32 + (lane&31)]
__global__ __launch_bounds__(256, 4)
void prep_kernel(const float* __restrict__ Kg, const float* __restrict__ Vg,
                 unsigned short* __restrict__ Kws, unsigned short* __restrict__ Vws) {
    __shared__ float Vf[64][65];
    const int tid = threadIdx.x;
    const int bid = blockIdx.x;
    if (bid < 1024) {  // ---- K ----
        const int h = bid >> 7, t = bid & 127;
        unsigned short* dst = Kws + (size_t)bid * SLAB;
#pragma unroll
        for (int j = 0; j < 2; ++j) {
            const int m = tid * 2 + j;
            const int instr = m >> 6, ln = m & 63;
            const int kh = instr >> 2, kd = instr & 3;
            const int row = t * 64 + kh * 32 + (ln & 31);
            const int col = kd * 16 + (ln >> 5) * 8;
            const float* src = Kg + ((size_t)row * NH + h) * DIM + col;
            float4 a = ((const float4*)src)[0];
            float4 b = ((const float4*)src)[1];
            u32x4 w;
            w[0] = cvt_pk(a.x, a.y); w[1] = cvt_pk(a.z, a.w);
            w[2] = cvt_pk(b.x, b.y); w[3] = cvt_pk(b.z, b.w);
            *(u32x4*)(dst + m * 8) = w;
        }
    } else {           // ---- V: transpose via LDS ----
        const int hb = bid - 1024;
        const int h = hb >> 7, t = hb & 127;
        const int key = tid >> 2, dc = (tid & 3) * 16;
        const float* src = Vg + ((size_t)(t * 64 + key) * NH + h) * DIM + dc;
#pragma unroll
        for (int i = 0; i < 4; ++i) {
            float4 a = ((const float4*)src)[i];
            Vf[key][dc + i * 4 + 0] = a.x; Vf[key][dc + i * 4 + 1] = a.y;
            Vf[key][dc + i * 4 + 2] = a.z; Vf[key][dc + i * 4 + 3] = a.w;
        }
        __syncthreads();
        unsigned short* dst = Vws + (size_t)hb * SLAB;
#pragma unroll
        for (int j = 0; j < 2; ++j) {
            const int m = tid * 2 + j;
            const int instr = m >> 6, ln = m & 63;
            const int vh = instr >> 2, ks = instr & 3;
            const int d  = vh * 32 + (ln & 31);
            const int k0 = ks * 16 + (ln >> 5) * 8;
            u32x4 w;
            w[0] = cvt_pk(Vf[k0 + 0][d], Vf[k0 + 1][d]);
            w[1] = cvt_pk(Vf[k0 + 2][d], Vf[k0 + 3][d]);
            w[2] = cvt_pk(Vf[k0 + 4][d], Vf[k0 + 5][d]);
            w[3] = cvt_pk(Vf[k0 + 6][d], Vf[k0 + 7][d]);
            *(u32x4*)(dst + m * 8) = w;
        }
    }
}

// ============ main: r9 structure, 4 waves = 2 KV-halves x 2 q-waves x 64 q-rows ============
__global__ __launch_bounds__(256, 2)
void fa_kernel(const float* __restrict__ Qg, const unsigned short* __restrict__ Kws,
               const unsigned short* __restrict__ Vws, float* __restrict__ Og) {
    __shared__ unsigned short KVb[2][2][2][SLAB];  // [K/V][half][dbuf][slab] = 64KB
    __shared__ float mrgML[2][2][128];             // [grp][m/l][row] 2KB

    const int tid  = threadIdx.x;
    const int lane = tid & 63;
    const int wave = tid >> 6;       // 0..3
    const int half_f = wave >> 1;    // KV-half
    const int qv_f   = wave & 1;     // q-wave within half (64 rows)
    const int la31 = lane & 31;
    const int hi   = lane >> 5;
    const int halftid = tid & 127;   // 2 waves per half stage the slab
    const int head  = blockIdx.x & 7;    // head pinned per XCD
    const int qtile = blockIdx.x >> 3;
    const int qbase = qtile * 128 + qv_f * 64;
    const int fragoff = lane * 8;

    // ---- persistent Q fragments, 2 groups x 32 rows ----
    bf16x8 qf[2][4];
#pragma unroll
    for (int g = 0; g < 2; ++g)
#pragma unroll
        for (int kd = 0; kd < 4; ++kd) {
            const float* qp = Qg + ((size_t)(qbase + g * 32 + la31) * NH + head) * DIM + kd * 16 + hi * 8;
            float4 a = ((const float4*)qp)[0];
            float4 b = ((const float4*)qp)[1];
            u32x4 w;
            w[0] = cvt_pk(a.x * SCL2, a.y * SCL2);
            w[1] = cvt_pk(a.z * SCL2, a.w * SCL2);
            w[2] = cvt_pk(b.x * SCL2, b.y * SCL2);
            w[3] = cvt_pk(b.z * SCL2, b.w * SCL2);
            qf[g][kd] = __builtin_bit_cast(bf16x8, w);
        }

    const unsigned short* ksl = Kws + ((size_t)head * NT + (size_t)half_f * NTH) * SLAB + halftid * 8;
    const unsigned short* vsl = Vws + ((size_t)head * NT + (size_t)half_f * NTH) * SLAB + halftid * 8;

    const f32x16 ZERO = {0.f,0.f,0.f,0.f,0.f,0.f,0.f,0.f,0.f,0.f,0.f,0.f,0.f,0.f,0.f,0.f};
    f32x16 oacc[2][2];
#pragma unroll
    for (int g = 0; g < 2; ++g)
#pragma unroll
        for (int nt = 0; nt < 2; ++nt) oacc[g][nt] = ZERO;
    float m_run[2] = {-1e30f, -1e30f}, l_run[2] = {0.f, 0.f};

    // prologue: load this half's tile 0 (4 chunks K, 4 chunks V per thread)
    u16x8 kr0 = *(const u16x8*)ksl,          kr1 = *(const u16x8*)(ksl + 1024);
    u16x8 kr2 = *(const u16x8*)(ksl + 2048), kr3 = *(const u16x8*)(ksl + 3072);
    u16x8 vr0 = *(const u16x8*)vsl,          vr1 = *(const u16x8*)(vsl + 1024);
    u16x8 vr2 = *(const u16x8*)(vsl + 2048), vr3 = *(const u16x8*)(vsl + 3072);
    ksl += SLAB; vsl += SLAB;

    for (int t = 0; t < NTH; ++t) {
        const int cur = t & 1;
        unsigned short* kw = &KVb[0][half_f][cur][0];
        unsigned short* vw = &KVb[1][half_f][cur][0];
        *(u16x8*)(kw + halftid * 8)        = kr0;
        *(u16x8*)(kw + 1024 + halftid * 8) = kr1;
        *(u16x8*)(kw + 2048 + halftid * 8) = kr2;
        *(u16x8*)(kw + 3072 + halftid * 8) = kr3;
        *(u16x8*)(vw + halftid * 8)        = vr0;
        *(u16x8*)(vw + 1024 + halftid * 8) = vr1;
        *(u16x8*)(vw + 2048 + halftid * 8) = vr2;
        *(u16x8*)(vw + 3072 + halftid * 8) = vr3;
        __syncthreads();
        if (t + 1 < NTH) {
            kr0 = *(const u16x8*)ksl;          kr1 = *(const u16x8*)(ksl + 1024);
            kr2 = *(const u16x8*)(ksl + 2048); kr3 = *(const u16x8*)(ksl + 3072);
            vr0 = *(const u16x8*)vsl;          vr1 = *(const u16x8*)(vsl + 1024);
            vr2 = *(const u16x8*)(vsl + 2048); vr3 = *(const u16x8*)(vsl + 3072);
            ksl += SLAB; vsl += SLAB;
        }
        const unsigned short* Kbase = &KVb[0][half_f][cur][0];
        const unsigned short* Vbase = &KVb[1][half_f][cur][0];

        // ---- QK^T for both groups: 8 ds_read, 16 MFMA (ZERO-seeded, no mov storm) ----
        f32x16 s00, s01, s10, s11;
        __builtin_amdgcn_s_setprio(1);
        {
            bf16x8 k0 = *(const bf16x8*)(Kbase + fragoff);
            bf16x8 k1 = *(const bf16x8*)(Kbase + 4 * 512 + fragoff);
            s00 = MFMA32(k0, qf[0][0], ZERO);
            s01 = MFMA32(k1, qf[0][0], ZERO);
            s10 = MFMA32(k0, qf[1][0], ZERO);
            s11 = MFMA32(k1, qf[1][0], ZERO);
        }
#pragma unroll
        for (int kd = 1; kd < 4; ++kd) {
            bf16x8 k0 = *(const bf16x8*)(Kbase + kd * 512 + fragoff);
            bf16x8 k1 = *(const bf16x8*)(Kbase + (4 + kd) * 512 + fragoff);
            s00 = MFMA32(k0, qf[0][kd], s00);
            s01 = MFMA32(k1, qf[0][kd], s01);
            s10 = MFMA32(k0, qf[1][kd], s10);
            s11 = MFMA32(k1, qf[1][kd], s11);
        }
        __builtin_amdgcn_s_setprio(0);

        // ---- per-group max (max3 tree, lane-local) + defer-max rescale ----
#pragma unroll
        for (int g = 0; g < 2; ++g) {
            const f32x16& a = g ? s10 : s00;
            const f32x16& b = g ? s11 : s01;
            float pmv[16];
#pragma unroll
            for (int i = 0; i < 16; ++i) pmv[i] = fmaxf(a[i], b[i]);
            float t0 = max3f(pmv[0], pmv[1], pmv[2]);
            float t1 = max3f(pmv[3], pmv[4], pmv[5]);
            float t2 = max3f(pmv[6], pmv[7], pmv[8]);
            float t3 = max3f(pmv[9], pmv[10], pmv[11]);
            float t4 = max3f(pmv[12], pmv[13], pmv[14]);
            float u0 = max3f(t0, t1, pmv[15]);
            float u1 = max3f(t2, t3, t4);
            float pm = fmaxf(u0, u1);
            // lane-local test; __any covers both pair lanes -> wave-uniform branch
            if (__any(pm > m_run[g] + 8.f)) {
                float pmx = fmaxf(pm, __shfl_xor(pm, 32));  // pair-combine only here
                float mnew = fmaxf(m_run[g], pmx);
                float corr = exp2f_fast(m_run[g] - mnew);
                m_run[g] = mnew;
                l_run[g] *= corr;
#pragma unroll
                for (int i = 0; i < 16; ++i) { oacc[g][0][i] *= corr; oacc[g][1][i] *= corr; }
            }
        }

        // ---- per key-block: exp+pack both groups, then 8 shared-V MFMAs ----
#pragma unroll
        for (int kb = 0; kb < 2; ++kb) {
            bf16x8 frg[2][2];
#pragma unroll
            for (int g = 0; g < 2; ++g) {
                const f32x16& s = g ? (kb ? s11 : s10) : (kb ? s01 : s00);
                float p[16];
#pragma unroll
                for (int i = 0; i < 16; ++i) p[i] = exp2f_fast(s[i] - m_run[g]);
                float ts[8];
#pragma unroll
                for (int i = 0; i < 8; ++i) ts[i] = p[i] + p[i + 8];
#pragma unroll
                for (int i = 0; i < 4; ++i) ts[i] += ts[i + 4];
                l_run[g] += (ts[0] + ts[1]) + (ts[2] + ts[3]);
                unsigned A[8];
#pragma unroll
                for (int j = 0; j < 8; ++j) A[j] = cvt_pk(p[2 * j], p[2 * j + 1]);
                pl32swap(A[0], A[2]); pl32swap(A[1], A[3]);
                pl32swap(A[4], A[6]); pl32swap(A[5], A[7]);
                u32x4 f0v; f0v[0] = A[0]; f0v[1] = A[1]; f0v[2] = A[2]; f0v[3] = A[3];
                u32x4 f1v; f1v[0] = A[4]; f1v[1] = A[5]; f1v[2] = A[6]; f1v[3] = A[7];
                frg[g][0] = __builtin_bit_cast(bf16x8, f0v);
                frg[g][1] = __builtin_bit_cast(bf16x8, f1v);
            }
            __builtin_amdgcn_s_setprio(1);
#pragma unroll
            for (int ks2 = 0; ks2 < 2; ++ks2) {
                const int ksg = kb * 2 + ks2;
                bf16x8 vf0 = *(const bf16x8*)(Vbase + ksg * 512 + fragoff);
                bf16x8 vf1 = *(const bf16x8*)(Vbase + (4 + ksg) * 512 + fragoff);
                oacc[0][0] = MFMA32(vf0, frg[0][ks2], oacc[0][0]);
                oacc[0][1] = MFMA32(vf1, frg[0][ks2], oacc[0][1]);
                oacc[1][0] = MFMA32(vf0, frg[1][ks2], oacc[1][0]);
                oacc[1][1] = MFMA32(vf1, frg[1][ks2], oacc[1][1]);
            }
            __builtin_amdgcn_s_setprio(0);
        }
    }

    // ---- merge the two KV-halves (max-aware); mrgO reuses the 64KB KV buffer ----
    __syncthreads();
    float* mrgO = (float*)&KVb[0][0][0][0];  // [hi][val 0..31][row 0..127]
    const int row0 = qv_f * 64;
    if (half_f) {
#pragma unroll
        for (int g = 0; g < 2; ++g) {
            const int row = row0 + g * 32 + la31;
#pragma unroll
            for (int nt = 0; nt < 2; ++nt)
#pragma unroll
                for (int i = 0; i < 16; ++i)
                    mrgO[hi * 4096 + (nt * 16 + i) * 128 + row] = oacc[g][nt][i];
            mrgML[g][0][qv_f * 64 + lane] = m_run[g];
            mrgML[g][1][qv_f * 64 + lane] = l_run[g];
        }
    }
    __syncthreads();
    if (!half_f) {
#pragma unroll
        for (int g = 0; g < 2; ++g) {
            const int row = row0 + g * 32 + la31;
            const float m1 = mrgML[g][0][qv_f * 64 + lane];
            const float l1 = mrgML[g][1][qv_f * 64 + lane];
            const float mnew = fmaxf(m_run[g], m1);
            const float c0 = exp2f_fast(m_run[g] - mnew);
            const float c1 = exp2f_fast(m1 - mnew);
            float lt = l_run[g] * c0 + l1 * c1;
#pragma unroll
            for (int nt = 0; nt < 2; ++nt)
#pragma unroll
                for (int i = 0; i < 16; ++i)
                    oacc[g][nt][i] = oacc[g][nt][i] * c0 + mrgO[hi * 4096 + (nt * 16 + i) * 128 + row] * c1;
            const float l_tot = lt + __shfl_xor(lt, 32);
            const float inv = __builtin_amdgcn_rcpf(l_tot);
            float* obase = Og + ((size_t)(qtile * 128 + row) * NH + head) * DIM;
#pragma unroll
            for (int nt = 0; nt < 2; ++nt)
#pragma unroll
                for (int rq = 0; rq < 4; ++rq) {
                    float4 o;
                    o.x = oacc[g][nt][rq * 4 + 0] * inv;
                    o.y = oacc[g][nt][rq * 4 + 1] * inv;
                    o.z = oacc[g][nt][rq * 4 + 2] * inv;
                    o.w = oacc[g][nt][rq * 4 + 3] * inv;
                    *(float4*)(obase + nt * 32 + rq * 8 + hi * 4) = o;
                }
        }
    }
}

// ============ fallback (round-4 proven kernel) if ws too small ============
__global__ __launch_bounds__(256, 2)
void fb_kernel(const float* __restrict__ Qg, const float* __restrict__ Kg,
               const float* __restrict__ Vg, float* __restrict__ Og) {
    __shared__ unsigned short Kl[KVB][DIM];
    __shared__ unsigned short Vt[DIM][KVB];
    unsigned short* Kbase = &Kl[0][0];
    unsigned short* Vbase = &Vt[0][0];
    const int tid  = threadIdx.x;
    const int lane = tid & 63;
    const int wave = tid >> 6;
    const int la31 = lane & 31;
    const int hi   = lane >> 5;
    const int head  = blockIdx.x & 7;
    const int qtile = blockIdx.x >> 3;
    const int q     = qtile * 128 + wave * 32 + la31;
    bf16x8 qf[4];
#pragma unroll
    for (int kd = 0; kd < 4; ++kd) {
        const float* qp = Qg + ((size_t)q * NH + head) * DIM + kd * 16 + hi * 8;
        float4 a = ((const float4*)qp)[0];
        float4 b = ((const float4*)qp)[1];
        u32x4 w;
        w[0] = cvt_pk(a.x * SCL2, a.y * SCL2);
        w[1] = cvt_pk(a.z * SCL2, a.w * SCL2);
        w[2] = cvt_pk(b.x * SCL2, b.y * SCL2);
        w[3] = cvt_pk(b.z * SCL2, b.w * SCL2);
        qf[kd] = __builtin_bit_cast(bf16x8, w);
    }
    const int ksrow = tid & 63;
    const int kscol = (tid >> 6) * 16;
    const int vpair = tid & 31;
    const int vcg   = tid >> 5;
    const float* kptr  = Kg + ((size_t)ksrow * NH + head) * DIM + kscol;
    const float* vptr0 = Vg + ((size_t)(2 * vpair) * NH + head) * DIM + vcg * 8;
    const float* vptr1 = vptr0 + NH * DIM;
    constexpr size_t STRIDE = (size_t)KVB * NH * DIM;
    const int kIdx0 = swz(ksrow, kscol);
    const int kIdx1 = swz(ksrow, kscol + 8);
    f32x16 oacc[2];
#pragma unroll
    for (int nt = 0; nt < 2; ++nt)
#pragma unroll
        for (int i = 0; i < 16; ++i) oacc[nt][i] = 0.f;
    float m_run = -1e30f, l_run = 0.f;
    float4 kr0 = ((const float4*)kptr)[0], kr1 = ((const float4*)kptr)[1];
    float4 kr2 = ((const float4*)kptr)[2], kr3 = ((const float4*)kptr)[3];
    float4 va0 = ((const float4*)vptr0)[0], va1 = ((const float4*)vptr0)[1];
    float4 vb0 = ((const float4*)vptr1)[0], vb1 = ((const float4*)vptr1)[1];
    kptr += STRIDE; vptr0 += STRIDE; vptr1 += STRIDE;
    for (int t = 0; t < NT; ++t) {
        __syncthreads();
        {
            u32x4 w;
            w[0] = cvt_pk(kr0.x, kr0.y); w[1] = cvt_pk(kr0.z, kr0.w);
            w[2] = cvt_pk(kr1.x, kr1.y); w[3] = cvt_pk(kr1.z, kr1.w);
            *(u32x4*)(Kbase + kIdx0) = w;
            w[0] = cvt_pk(kr2.x, kr2.y); w[1] = cvt_pk(kr2.z, kr2.w);
            w[2] = cvt_pk(kr3.x, kr3.y); w[3] = cvt_pk(kr3.z, kr3.w);
            *(u32x4*)(Kbase + kIdx1) = w;
        }
        {
            *(unsigned*)(Vbase + swz(vcg * 8 + 0, 2 * vpair)) = cvt_pk(va0.x, vb0.x);
            *(unsigned*)(Vbase + swz(vcg * 8 + 1, 2 * vpair)) = cvt_pk(va0.y, vb0.y);
            *(unsigned*)(Vbase + swz(vcg * 8 + 2, 2 * vpair)) = cvt_pk(va0.z, vb0.z);
            *(unsigned*)(Vbase + swz(vcg * 8 + 3, 2 * vpair)) = cvt_pk(va0.w, vb0.w);
            *(unsigned*)(Vbase + swz(vcg * 8 + 4, 2 * vpair)) = cvt_pk(va1.x, vb1.x);
            *(unsigned*)(Vbase + swz(vcg * 8 + 5, 2 * vpair)) = cvt_pk(va1.y, vb1.y);
            *(unsigned*)(Vbase + swz(vcg * 8 + 6, 2 * vpair)) = cvt_pk(va1.z, vb1.z);
            *(unsigned*)(Vbase + swz(vcg * 8 + 7, 2 * vpair)) = cvt_pk(va1.w, vb1.w);
        }
        __syncthreads();
        if (t + 1 < NT) {
            kr0 = ((const float4*)kptr)[0]; kr1 = ((const float4*)kptr)[1];
            kr2 = ((const float4*)kptr)[2]; kr3 = ((const float4*)kptr)[3];
            va0 = ((const float4*)vptr0)[0]; va1 = ((const float4*)vptr0)[1];
            vb0 = ((const float4*)vptr1)[0]; vb1 = ((const float4*)vptr1)[1];
            kptr += STRIDE; vptr0 += STRIDE; vptr1 += STRIDE;
        }
        f32x16 s0, s1;
#pragma unroll
        for (int i = 0; i < 16; ++i) { s0[i] = 0.f; s1[i] = 0.f; }
        __builtin_amdgcn_s_setprio(1);
#pragma unroll
        for (int kd = 0; kd < 4; ++kd) {
            bf16x8 k0 = *(const bf16x8*)(Kbase + swz(la31, kd * 16 + hi * 8));
            bf16x8 k1 = *(const bf16x8*)(Kbase + swz(32 + la31, kd * 16 + hi * 8));
            s0 = MFMA32(k0, qf[kd], s0);
            s1 = MFMA32(k1, qf[kd], s1);
        }
        __builtin_amdgcn_s_setprio(0);
        float pmv[16];
#pragma unroll
        for (int i = 0; i < 16; ++i) pmv[i] = fmaxf(s0[i], s1[i]);
#pragma unroll
        for (int st = 8; st >= 1; st >>= 1)
#pragma unroll
            for (int i = 0; i < 8; ++i)
                if (i < st) pmv[i] = fmaxf(pmv[i], pmv[i + st]);
        float pm = pmv[0];
        pm = fmaxf(pm, __shfl_xor(pm, 32));
        if (__any(pm > m_run + 8.f)) {
            float mnew = fmaxf(m_run, pm);
            float corr = exp2f_fast(m_run - mnew);
            m_run = mnew;
            l_run *= corr;
#pragma unroll
            for (int i = 0; i < 16; ++i) { oacc[0][i] *= corr; oacc[1][i] *= corr; }
        }
#pragma unroll
        for (int kb = 0; kb < 2; ++kb) {
            const f32x16& s = kb ? s1 : s0;
            float p[16];
#pragma unroll
            for (int i = 0; i < 16; ++i) p[i] = exp2f_fast(s[i] - m_run);
            float ts[8];
#pragma unroll
            for (int i = 0; i < 8; ++i) ts[i] = p[i] + p[i + 8];
#pragma unroll
            for (int i = 0; i < 4; ++i) ts[i] += ts[i + 4];
            l_run += (ts[0] + ts[1]) + (ts[2] + ts[3]);
            unsigned A[8];
#pragma unroll
            for (int j = 0; j < 8; ++j) A[j] = cvt_pk(p[2 * j], p[2 * j + 1]);
            pl32swap(A[0], A[2]); pl32swap(A[1], A[3]);
            pl32swap(A[4], A[6]); pl32swap(A[5], A[7]);
            u32x4 f0v; f0v[0] = A[0]; f0v[1] = A[1]; f0v[2] = A[2]; f0v[3] = A[3];
            u32x4 f1v; f1v[0] = A[4]; f1v[1] = A[5]; f1v[2] = A[6]; f1v[3] = A[7];
            bf16x8 frag[2] = { __builtin_bit_cast(bf16x8, f0v), __builtin_bit_cast(bf16x8, f1v) };
            __builtin_amdgcn_s_setprio(1);
#pragma unroll
            for (int ksl = 0; ksl < 2; ++ksl) {
                const int ksg = kb * 2 + ksl;
                bf16x8 vf0 = *(const bf16x8*)(Vbase + swz(la31, ksg * 16 + hi * 8));
                bf16x8 vf1 = *(const bf16x8*)(Vbase + swz(32 + la31, ksg * 16 + hi * 8));
                oacc[0] = MFMA32(vf0, frag[ksl], oacc[0]);
                oacc[1] = MFMA32(vf1, frag[ksl], oacc[1]);
            }
            __builtin_amdgcn_s_setprio(0);
        }
    }
    {
        float l_tot = l_run + __shfl_xor(l_run, 32);
        float inv = __builtin_amdgcn_rcpf(l_tot);
        float* obase = Og + ((size_t)q * NH + head) * DIM;
#pragma unroll
        for (int nt = 0; nt < 2; ++nt)
#pragma unroll
            for (int rq = 0; rq < 4; ++rq) {
                float4 o;
                o.x = oacc[nt][rq * 4 + 0] * inv;
                o.y = oacc[nt][rq * 4 + 1] * inv;
                o.z = oacc[nt][rq * 4 + 2] * inv;
                o.w = oacc[nt][rq * 4 + 3] * inv;
                *(float4*)(obase + nt * 32 + rq * 8 + hi * 4) = o;
            }
    }
}

extern "C" void kernel_launch(void* const* d_in, const int* in_sizes, int n_in,
                              void* d_out, int out_size, void* d_ws, size_t ws_size,
                              hipStream_t stream) {
    const float* q = (const float*)d_in[0];
    const float* k = (const float*)d_in[1];
    const float* v = (const float*)d_in[2];
    float* out = (float*)d_out;
    constexpr size_t KV_WS = 2ull * NH * NT * SLAB * sizeof(unsigned short);  // 16.78 MB
    if (ws_size >= KV_WS) {
        unsigned short* Kws = (unsigned short*)d_ws;
        unsigned short* Vws = Kws + (size_t)NH * NT * SLAB;
        hipLaunchKernelGGL(prep_kernel, dim3(2048), dim3(256), 0, stream, k, v, Kws, Vws);
        hipLaunchKernelGGL(fa_kernel, dim3(512), dim3(256), 0, stream, q, Kws, Vws, out);
    } else {
        hipLaunchKernelGGL(fb_kernel, dim3(512), dim3(256), 0, stream, q, k, v, out);
    }
}

// Round 12
// 181.780 us; speedup vs baseline: 1.0549x; 1.0320x over previous
//
#include <hip/hip_runtime.h>
#include <hip/hip_bf16.h>

typedef __attribute__((ext_vector_type(8))) short bf16x8;
typedef __attribute__((ext_vector_type(8))) unsigned short u16x8;
typedef __attribute__((ext_vector_type(16))) float f32x16;
typedef __attribute__((ext_vector_type(4))) unsigned int u32x4;

#define MFMA32(a, b, c) __builtin_amdgcn_mfma_f32_32x32x16_bf16(a, b, c, 0, 0, 0)

constexpr int NSEQ = 8192;
constexpr int NH   = 8;
constexpr int DIM  = 64;
constexpr int KVB  = 64;
constexpr int NT   = NSEQ / KVB;         // 128 tiles
constexpr int NTH  = NT / 2;             // 64 tiles per KV-half
constexpr int SLAB = KVB * DIM;          // 4096 ushorts = 8KB per tile slab
constexpr float SCL2 = 0.18033688011112042f;  // 0.125 * log2(e)

__device__ __forceinline__ unsigned cvt_pk(float lo, float hi) {
    unsigned r;
    asm("v_cvt_pk_bf16_f32 %0, %1, %2" : "=v"(r) : "v"(lo), "v"(hi));
    return r;
}
__device__ __forceinline__ float exp2f_fast(float x) {
    float r;
    asm("v_exp_f32 %0, %1" : "=v"(r) : "v"(x));
    return r;
}
// safe ONLY with provably-distinct operands (distinct live values)
__device__ __forceinline__ void pl32swap(unsigned& a, unsigned& b) {
    asm("v_permlane32_swap_b32 %0, %1" : "+v"(a), "+v"(b));
}
// (fallback kernel only) XOR-swizzled LDS index for [row][64] bf16 tiles
__device__ __forceinline__ int swz(int row, int col) {
    return row * 64 + ((((col >> 3) ^ row) & 7) << 3) + (col & 7);
}

// ============ prep: fp32 K/V -> bf16 slabs in FRAGMENT-READ order ============
// Slab = 8 wave-instructions x 64 lanes x 16B, linear:
//   K chunk(instr=kh*4+kd, lane): K[t*64 + kh*32 + (lane&31)][h][kd*16 + (lane>>5)*8 + 0..7]
//   V chunk(instr=vh*4+ks, lane): V[t*64 + ks*16 + (lane>>5)*8 + 0..7][h][vh*32 + (lane&31)]
__global__ __launch_bounds__(256, 4)
void prep_kernel(const float* __restrict__ Kg, const float* __restrict__ Vg,
                 unsigned short* __restrict__ Kws, unsigned short* __restrict__ Vws) {
    __shared__ float Vf[64][65];
    const int tid = threadIdx.x;
    const int bid = blockIdx.x;
    if (bid < 1024) {  // ---- K ----
        const int h = bid >> 7, t = bid & 127;
        unsigned short* dst = Kws + (size_t)bid * SLAB;
#pragma unroll
        for (int j = 0; j < 2; ++j) {
            const int m = tid * 2 + j;                 // chunk 0..511
            const int instr = m >> 6, ln = m & 63;
            const int kh = instr >> 2, kd = instr & 3;
            const int row = t * 64 + kh * 32 + (ln & 31);
            const int col = kd * 16 + (ln >> 5) * 8;
            const float* src = Kg + ((size_t)row * NH + h) * DIM + col;
            float4 a = ((const float4*)src)[0];
            float4 b = ((const float4*)src)[1];
            u32x4 w;
            w[0] = cvt_pk(a.x, a.y); w[1] = cvt_pk(a.z, a.w);
            w[2] = cvt_pk(b.x, b.y); w[3] = cvt_pk(b.z, b.w);
            *(u32x4*)(dst + m * 8) = w;
        }
    } else {           // ---- V: transpose via LDS ----
        const int hb = bid - 1024;
        const int h = hb >> 7, t = hb & 127;
        const int key = tid >> 2, dc = (tid & 3) * 16;
        const float* src = Vg + ((size_t)(t * 64 + key) * NH + h) * DIM + dc;
#pragma unroll
        for (int i = 0; i < 4; ++i) {
            float4 a = ((const float4*)src)[i];
            Vf[key][dc + i * 4 + 0] = a.x; Vf[key][dc + i * 4 + 1] = a.y;
            Vf[key][dc + i * 4 + 2] = a.z; Vf[key][dc + i * 4 + 3] = a.w;
        }
        __syncthreads();
        unsigned short* dst = Vws + (size_t)hb * SLAB;
#pragma unroll
        for (int j = 0; j < 2; ++j) {
            const int m = tid * 2 + j;
            const int instr = m >> 6, ln = m & 63;
            const int vh = instr >> 2, ks = instr & 3;
            const int d  = vh * 32 + (ln & 31);
            const int k0 = ks * 16 + (ln >> 5) * 8;
            u32x4 w;
            w[0] = cvt_pk(Vf[k0 + 0][d], Vf[k0 + 1][d]);
            w[1] = cvt_pk(Vf[k0 + 2][d], Vf[k0 + 3][d]);
            w[2] = cvt_pk(Vf[k0 + 4][d], Vf[k0 + 5][d]);
            w[3] = cvt_pk(Vf[k0 + 6][d], Vf[k0 + 7][d]);
            *(u32x4*)(dst + m * 8) = w;
        }
    }
}

// ============ main: 4 waves = 2 KV-halves x 2 q-waves x 64 q-rows (2 groups) ============
__global__ __launch_bounds__(512, 2)
void fa_kernel(const float* __restrict__ Qg, const unsigned short* __restrict__ Kws,
               const unsigned short* __restrict__ Vws, float* __restrict__ Og) {
    __shared__ unsigned short KVb[2][2][2][SLAB];  // [K/V][half][dbuf][slab] = 64KB
    __shared__ float mrgML[2][2][256];             // [grp][m/l][row]

    const int tid  = threadIdx.x;
    const int lane = tid & 63;
    const int wave = tid >> 6;       // 0..3
    const int la31 = lane & 31;
    const int hi   = lane >> 5;
    const int head  = blockIdx.x & 7;    // head pinned per XCD (4MB KV slab = XCD L2)
    const int qtile = blockIdx.x >> 3;
    const int fragoff = lane * 8;

    // block = 256 threads = 4 waves = 2 halves x 2 q-waves. half = wave>>1, qv = wave&1.
    const int half_f  = wave >> 1;
    const int qv_f    = wave & 1;
    const int qbase_f = qtile * 128 + qv_f * 64;
    const int halftid_f = tid & 127;   // 2 waves per half stage the slab

    // ---- persistent Q fragments for both groups ----
    bf16x8 qf[2][4];
#pragma unroll
    for (int g = 0; g < 2; ++g)
#pragma unroll
        for (int kd = 0; kd < 4; ++kd) {
            const float* qp = Qg + ((size_t)(qbase_f + g * 32 + la31) * NH + head) * DIM + kd * 16 + hi * 8;
            float4 a = ((const float4*)qp)[0];
            float4 b = ((const float4*)qp)[1];
            u32x4 w;
            w[0] = cvt_pk(a.x * SCL2, a.y * SCL2);
            w[1] = cvt_pk(a.z * SCL2, a.w * SCL2);
            w[2] = cvt_pk(b.x * SCL2, b.y * SCL2);
            w[3] = cvt_pk(b.z * SCL2, b.w * SCL2);
            qf[g][kd] = __builtin_bit_cast(bf16x8, w);
        }

    // staging: 128 threads per half stage 8KB K + 8KB V per tile (4 chunks each)
    const unsigned short* ksl = Kws + ((size_t)head * NT + (size_t)half_f * NTH) * SLAB + halftid_f * 8;
    const unsigned short* vsl = Vws + ((size_t)head * NT + (size_t)half_f * NTH) * SLAB + halftid_f * 8;

    f32x16 oacc[2][2];
#pragma unroll
    for (int g = 0; g < 2; ++g)
#pragma unroll
        for (int nt = 0; nt < 2; ++nt)
#pragma unroll
            for (int i = 0; i < 16; ++i) oacc[g][nt][i] = 0.f;
    float m_run[2] = {-1e30f, -1e30f}, l_run[2] = {0.f, 0.f};

    // prologue: load this half's tile 0 (4 chunks K, 4 chunks V per thread)
    u16x8 kr0 = *(const u16x8*)ksl,          kr1 = *(const u16x8*)(ksl + 1024);
    u16x8 kr2 = *(const u16x8*)(ksl + 2048), kr3 = *(const u16x8*)(ksl + 3072);
    u16x8 vr0 = *(const u16x8*)vsl,          vr1 = *(const u16x8*)(vsl + 1024);
    u16x8 vr2 = *(const u16x8*)(vsl + 2048), vr3 = *(const u16x8*)(vsl + 3072);
    ksl += SLAB; vsl += SLAB;

    for (int t = 0; t < NTH; ++t) {
        const int cur = t & 1;
        unsigned short* kw = &KVb[0][half_f][cur][0];
        unsigned short* vw = &KVb[1][half_f][cur][0];
        *(u16x8*)(kw + halftid_f * 8)        = kr0;
        *(u16x8*)(kw + 1024 + halftid_f * 8) = kr1;
        *(u16x8*)(kw + 2048 + halftid_f * 8) = kr2;
        *(u16x8*)(kw + 3072 + halftid_f * 8) = kr3;
        *(u16x8*)(vw + halftid_f * 8)        = vr0;
        *(u16x8*)(vw + 1024 + halftid_f * 8) = vr1;
        *(u16x8*)(vw + 2048 + halftid_f * 8) = vr2;
        *(u16x8*)(vw + 3072 + halftid_f * 8) = vr3;
        __syncthreads();
        if (t + 1 < NTH) {
            kr0 = *(const u16x8*)ksl;          kr1 = *(const u16x8*)(ksl + 1024);
            kr2 = *(const u16x8*)(ksl + 2048); kr3 = *(const u16x8*)(ksl + 3072);
            vr0 = *(const u16x8*)vsl;          vr1 = *(const u16x8*)(vsl + 1024);
            vr2 = *(const u16x8*)(vsl + 2048); vr3 = *(const u16x8*)(vsl + 3072);
            ksl += SLAB; vsl += SLAB;
        }
        const unsigned short* Kbase = &KVb[0][half_f][cur][0];
        const unsigned short* Vbase = &KVb[1][half_f][cur][0];

        // ---- QK^T for both groups: 8 ds_read, 16 MFMA ----
        f32x16 s00, s01, s10, s11;   // [grp][kh]
#pragma unroll
        for (int i = 0; i < 16; ++i) { s00[i] = 0.f; s01[i] = 0.f; s10[i] = 0.f; s11[i] = 0.f; }
        __builtin_amdgcn_s_setprio(1);
#pragma unroll
        for (int kd = 0; kd < 4; ++kd) {
            bf16x8 k0 = *(const bf16x8*)(Kbase + kd * 512 + fragoff);
            bf16x8 k1 = *(const bf16x8*)(Kbase + (4 + kd) * 512 + fragoff);
            s00 = MFMA32(k0, qf[0][kd], s00);
            s01 = MFMA32(k1, qf[0][kd], s01);
            s10 = MFMA32(k0, qf[1][kd], s10);
            s11 = MFMA32(k1, qf[1][kd], s11);
        }
        __builtin_amdgcn_s_setprio(0);

        // ---- per-group max + defer-max rescale ----
#pragma unroll
        for (int g = 0; g < 2; ++g) {
            const f32x16& a = g ? s10 : s00;
            const f32x16& b = g ? s11 : s01;
            float pmv[16];
#pragma unroll
            for (int i = 0; i < 16; ++i) pmv[i] = fmaxf(a[i], b[i]);
#pragma unroll
            for (int st = 8; st >= 1; st >>= 1)
#pragma unroll
                for (int i = 0; i < 8; ++i)
                    if (i < st) pmv[i] = fmaxf(pmv[i], pmv[i + st]);
            float pm = pmv[0];
            pm = fmaxf(pm, __shfl_xor(pm, 32));
            if (__any(pm > m_run[g] + 8.f)) {
                float mnew = fmaxf(m_run[g], pm);
                float corr = exp2f_fast(m_run[g] - mnew);
                m_run[g] = mnew;
                l_run[g] *= corr;
#pragma unroll
                for (int i = 0; i < 16; ++i) { oacc[g][0][i] *= corr; oacc[g][1][i] *= corr; }
            }
        }

        // ---- per key-block: exp+pack both groups, then 8 shared-V MFMAs ----
#pragma unroll
        for (int kb = 0; kb < 2; ++kb) {
            bf16x8 frg[2][2];
#pragma unroll
            for (int g = 0; g < 2; ++g) {
                const f32x16& s = g ? (kb ? s11 : s10) : (kb ? s01 : s00);
                float p[16];
#pragma unroll
                for (int i = 0; i < 16; ++i) p[i] = exp2f_fast(s[i] - m_run[g]);
                float ts[8];
#pragma unroll
                for (int i = 0; i < 8; ++i) ts[i] = p[i] + p[i + 8];
#pragma unroll
                for (int i = 0; i < 4; ++i) ts[i] += ts[i + 4];
                l_run[g] += (ts[0] + ts[1]) + (ts[2] + ts[3]);
                unsigned A[8];
#pragma unroll
                for (int j = 0; j < 8; ++j) A[j] = cvt_pk(p[2 * j], p[2 * j + 1]);
                pl32swap(A[0], A[2]); pl32swap(A[1], A[3]);
                pl32swap(A[4], A[6]); pl32swap(A[5], A[7]);
                u32x4 f0v; f0v[0] = A[0]; f0v[1] = A[1]; f0v[2] = A[2]; f0v[3] = A[3];
                u32x4 f1v; f1v[0] = A[4]; f1v[1] = A[5]; f1v[2] = A[6]; f1v[3] = A[7];
                frg[g][0] = __builtin_bit_cast(bf16x8, f0v);
                frg[g][1] = __builtin_bit_cast(bf16x8, f1v);
            }
            __builtin_amdgcn_s_setprio(1);
#pragma unroll
            for (int ks2 = 0; ks2 < 2; ++ks2) {
                const int ksg = kb * 2 + ks2;
                bf16x8 vf0 = *(const bf16x8*)(Vbase + ksg * 512 + fragoff);
                bf16x8 vf1 = *(const bf16x8*)(Vbase + (4 + ksg) * 512 + fragoff);
                oacc[0][0] = MFMA32(vf0, frg[0][ks2], oacc[0][0]);
                oacc[0][1] = MFMA32(vf1, frg[0][ks2], oacc[0][1]);
                oacc[1][0] = MFMA32(vf0, frg[1][ks2], oacc[1][0]);
                oacc[1][1] = MFMA32(vf1, frg[1][ks2], oacc[1][1]);
            }
            __builtin_amdgcn_s_setprio(0);
        }
    }

    // ---- merge the two KV-halves (max-aware); mrgO reuses the 64KB KV buffer ----
    __syncthreads();
    float* mrgO = (float*)&KVb[0][0][0][0];  // [hi][val 0..31][row 0..127]
    const int row0 = qv_f * 64;              // + g*32 + la31
    if (half_f) {
#pragma unroll
        for (int g = 0; g < 2; ++g) {
            const int row = row0 + g * 32 + la31;
#pragma unroll
            for (int nt = 0; nt < 2; ++nt)
#pragma unroll
                for (int i = 0; i < 16; ++i)
                    mrgO[hi * 4096 + (nt * 16 + i) * 128 + row] = oacc[g][nt][i];
            mrgML[g][0][qv_f * 64 + lane] = m_run[g];   // per-lane m (pair lanes equal)
            mrgML[g][1][qv_f * 64 + lane] = l_run[g];
        }
    }
    __syncthreads();
    if (!half_f) {
#pragma unroll
        for (int g = 0; g < 2; ++g) {
            const int row = row0 + g * 32 + la31;
            const float m1 = mrgML[g][0][qv_f * 64 + lane];
            const float l1 = mrgML[g][1][qv_f * 64 + lane];
            const float mnew = fmaxf(m_run[g], m1);
            const float c0 = exp2f_fast(m_run[g] - mnew);
            const float c1 = exp2f_fast(m1 - mnew);
            float lt = l_run[g] * c0 + l1 * c1;
#pragma unroll
            for (int nt = 0; nt < 2; ++nt)
#pragma unroll
                for (int i = 0; i < 16; ++i)
                    oacc[g][nt][i] = oacc[g][nt][i] * c0 + mrgO[hi * 4096 + (nt * 16 + i) * 128 + row] * c1;
            const float l_tot = lt + __shfl_xor(lt, 32);
            const float inv = __builtin_amdgcn_rcpf(l_tot);
            float* obase = Og + ((size_t)(qtile * 128 + row) * NH + head) * DIM;
#pragma unroll
            for (int nt = 0; nt < 2; ++nt)
#pragma unroll
                for (int rq = 0; rq < 4; ++rq) {
                    float4 o;
                    o.x = oacc[g][nt][rq * 4 + 0] * inv;
                    o.y = oacc[g][nt][rq * 4 + 1] * inv;
                    o.z = oacc[g][nt][rq * 4 + 2] * inv;
                    o.w = oacc[g][nt][rq * 4 + 3] * inv;
                    *(float4*)(obase + nt * 32 + rq * 8 + hi * 4) = o;
                }
        }
    }
}

// ============ fallback (round-4 proven kernel) if ws too small ============
__global__ __launch_bounds__(256, 2)
void fb_kernel(const float* __restrict__ Qg, const float* __restrict__ Kg,
               const float* __restrict__ Vg, float* __restrict__ Og) {
    __shared__ unsigned short Kl[KVB][DIM];
    __shared__ unsigned short Vt[DIM][KVB];
    unsigned short* Kbase = &Kl[0][0];
    unsigned short* Vbase = &Vt[0][0];
    const int tid  = threadIdx.x;
    const int lane = tid & 63;
    const int wave = tid >> 6;
    const int la31 = lane & 31;
    const int hi   = lane >> 5;
    const int head  = blockIdx.x & 7;
    const int qtile = blockIdx.x >> 3;
    const int q     = qtile * 128 + wave * 32 + la31;
    bf16x8 qf[4];
#pragma unroll
    for (int kd = 0; kd < 4; ++kd) {
        const float* qp = Qg + ((size_t)q * NH + head) * DIM + kd * 16 + hi * 8;
        float4 a = ((const float4*)qp)[0];
        float4 b = ((const float4*)qp)[1];
        u32x4 w;
        w[0] = cvt_pk(a.x * SCL2, a.y * SCL2);
        w[1] = cvt_pk(a.z * SCL2, a.w * SCL2);
        w[2] = cvt_pk(b.x * SCL2, b.y * SCL2);
        w[3] = cvt_pk(b.z * SCL2, b.w * SCL2);
        qf[kd] = __builtin_bit_cast(bf16x8, w);
    }
    const int ksrow = tid & 63;
    const int kscol = (tid >> 6) * 16;
    const int vpair = tid & 31;
    const int vcg   = tid >> 5;
    const float* kptr  = Kg + ((size_t)ksrow * NH + head) * DIM + kscol;
    const float* vptr0 = Vg + ((size_t)(2 * vpair) * NH + head) * DIM + vcg * 8;
    const float* vptr1 = vptr0 + NH * DIM;
    constexpr size_t STRIDE = (size_t)KVB * NH * DIM;
    const int kIdx0 = swz(ksrow, kscol);
    const int kIdx1 = swz(ksrow, kscol + 8);
    f32x16 oacc[2];
#pragma unroll
    for (int nt = 0; nt < 2; ++nt)
#pragma unroll
        for (int i = 0; i < 16; ++i) oacc[nt][i] = 0.f;
    float m_run = -1e30f, l_run = 0.f;
    float4 kr0 = ((const float4*)kptr)[0], kr1 = ((const float4*)kptr)[1];
    float4 kr2 = ((const float4*)kptr)[2], kr3 = ((const float4*)kptr)[3];
    float4 va0 = ((const float4*)vptr0)[0], va1 = ((const float4*)vptr0)[1];
    float4 vb0 = ((const float4*)vptr1)[0], vb1 = ((const float4*)vptr1)[1];
    kptr += STRIDE; vptr0 += STRIDE; vptr1 += STRIDE;
    for (int t = 0; t < NT; ++t) {
        __syncthreads();
        {
            u32x4 w;
            w[0] = cvt_pk(kr0.x, kr0.y); w[1] = cvt_pk(kr0.z, kr0.w);
            w[2] = cvt_pk(kr1.x, kr1.y); w[3] = cvt_pk(kr1.z, kr1.w);
            *(u32x4*)(Kbase + kIdx0) = w;
            w[0] = cvt_pk(kr2.x, kr2.y); w[1] = cvt_pk(kr2.z, kr2.w);
            w[2] = cvt_pk(kr3.x, kr3.y); w[3] = cvt_pk(kr3.z, kr3.w);
            *(u32x4*)(Kbase + kIdx1) = w;
        }
        {
            *(unsigned*)(Vbase + swz(vcg * 8 + 0, 2 * vpair)) = cvt_pk(va0.x, vb0.x);
            *(unsigned*)(Vbase + swz(vcg * 8 + 1, 2 * vpair)) = cvt_pk(va0.y, vb0.y);
            *(unsigned*)(Vbase + swz(vcg * 8 + 2, 2 * vpair)) = cvt_pk(va0.z, vb0.z);
            *(unsigned*)(Vbase + swz(vcg * 8 + 3, 2 * vpair)) = cvt_pk(va0.w, vb0.w);
            *(unsigned*)(Vbase + swz(vcg * 8 + 4, 2 * vpair)) = cvt_pk(va1.x, vb1.x);
            *(unsigned*)(Vbase + swz(vcg * 8 + 5, 2 * vpair)) = cvt_pk(va1.y, vb1.y);
            *(unsigned*)(Vbase + swz(vcg * 8 + 6, 2 * vpair)) = cvt_pk(va1.z, vb1.z);
            *(unsigned*)(Vbase + swz(vcg * 8 + 7, 2 * vpair)) = cvt_pk(va1.w, vb1.w);
        }
        __syncthreads();
        if (t + 1 < NT) {
            kr0 = ((const float4*)kptr)[0]; kr1 = ((const float4*)kptr)[1];
            kr2 = ((const float4*)kptr)[2]; kr3 = ((const float4*)kptr)[3];
            va0 = ((const float4*)vptr0)[0]; va1 = ((const float4*)vptr0)[1];
            vb0 = ((const float4*)vptr1)[0]; vb1 = ((const float4*)vptr1)[1];
            kptr += STRIDE; vptr0 += STRIDE; vptr1 += STRIDE;
        }
        f32x16 s0, s1;
#pragma unroll
        for (int i = 0; i < 16; ++i) { s0[i] = 0.f; s1[i] = 0.f; }
        __builtin_amdgcn_s_setprio(1);
#pragma unroll
        for (int kd = 0; kd < 4; ++kd) {
            bf16x8 k0 = *(const bf16x8*)(Kbase + swz(la31, kd * 16 + hi * 8));
            bf16x8 k1 = *(const bf16x8*)(Kbase + swz(32 + la31, kd * 16 + hi * 8));
            s0 = MFMA32(k0, qf[kd], s0);
            s1 = MFMA32(k1, qf[kd], s1);
        }
        __builtin_amdgcn_s_setprio(0);
        float pmv[16];
#pragma unroll
        for (int i = 0; i < 16; ++i) pmv[i] = fmaxf(s0[i], s1[i]);
#pragma unroll
        for (int st = 8; st >= 1; st >>= 1)
#pragma unroll
            for (int i = 0; i < 8; ++i)
                if (i < st) pmv[i] = fmaxf(pmv[i], pmv[i + st]);
        float pm = pmv[0];
        pm = fmaxf(pm, __shfl_xor(pm, 32));
        if (__any(pm > m_run + 8.f)) {
            float mnew = fmaxf(m_run, pm);
            float corr = exp2f_fast(m_run - mnew);
            m_run = mnew;
            l_run *= corr;
#pragma unroll
            for (int i = 0; i < 16; ++i) { oacc[0][i] *= corr; oacc[1][i] *= corr; }
        }
#pragma unroll
        for (int kb = 0; kb < 2; ++kb) {
            const f32x16& s = kb ? s1 : s0;
            float p[16];
#pragma unroll
            for (int i = 0; i < 16; ++i) p[i] = exp2f_fast(s[i] - m_run);
            float ts[8];
#pragma unroll
            for (int i = 0; i < 8; ++i) ts[i] = p[i] + p[i + 8];
#pragma unroll
            for (int i = 0; i < 4; ++i) ts[i] += ts[i + 4];
            l_run += (ts[0] + ts[1]) + (ts[2] + ts[3]);
            unsigned A[8];
#pragma unroll
            for (int j = 0; j < 8; ++j) A[j] = cvt_pk(p[2 * j], p[2 * j + 1]);
            pl32swap(A[0], A[2]); pl32swap(A[1], A[3]);
            pl32swap(A[4], A[6]); pl32swap(A[5], A[7]);
            u32x4 f0v; f0v[0] = A[0]; f0v[1] = A[1]; f0v[2] = A[2]; f0v[3] = A[3];
            u32x4 f1v; f1v[0] = A[4]; f1v[1] = A[5]; f1v[2] = A[6]; f1v[3] = A[7];
            bf16x8 frag[2] = { __builtin_bit_cast(bf16x8, f0v), __builtin_bit_cast(bf16x8, f1v) };
            __builtin_amdgcn_s_setprio(1);
#pragma unroll
            for (int ksl = 0; ksl < 2; ++ksl) {
                const int ksg = kb * 2 + ksl;
                bf16x8 vf0 = *(const bf16x8*)(Vbase + swz(la31, ksg * 16 + hi * 8));
                bf16x8 vf1 = *(const bf16x8*)(Vbase + swz(32 + la31, ksg * 16 + hi * 8));
                oacc[0] = MFMA32(vf0, frag[ksl], oacc[0]);
                oacc[1] = MFMA32(vf1, frag[ksl], oacc[1]);
            }
            __builtin_amdgcn_s_setprio(0);
        }
    }
    {
        float l_tot = l_run + __shfl_xor(l_run, 32);
        float inv = __builtin_amdgcn_rcpf(l_tot);
        float* obase = Og + ((size_t)q * NH + head) * DIM;
#pragma unroll
        for (int nt = 0; nt < 2; ++nt)
#pragma unroll
            for (int rq = 0; rq < 4; ++rq) {
                float4 o;
                o.x = oacc[nt][rq * 4 + 0] * inv;
                o.y = oacc[nt][rq * 4 + 1] * inv;
                o.z = oacc[nt][rq * 4 + 2] * inv;
                o.w = oacc[nt][rq * 4 + 3] * inv;
                *(float4*)(obase + nt * 32 + rq * 8 + hi * 4) = o;
            }
    }
}

extern "C" void kernel_launch(void* const* d_in, const int* in_sizes, int n_in,
                              void* d_out, int out_size, void* d_ws, size_t ws_size,
                              hipStream_t stream) {
    const float* q = (const float*)d_in[0];
    const float* k = (const float*)d_in[1];
    const float* v = (const float*)d_in[2];
    float* out = (float*)d_out;
    constexpr size_t KV_WS = 2ull * NH * NT * SLAB * sizeof(unsigned short);  // 16.78 MB
    if (ws_size >= KV_WS) {
        unsigned short* Kws = (unsigned short*)d_ws;
        unsigned short* Vws = Kws + (size_t)NH * NT * SLAB;
        hipLaunchKernelGGL(prep_kernel, dim3(2048), dim3(256), 0, stream, k, v, Kws, Vws);
        // block = 256 threads = 4 waves = 2 KV-halves x 2 q-waves x 64 q-rows (QB=128)
        hipLaunchKernelGGL(fa_kernel, dim3(512), dim3(256), 0, stream, q, Kws, Vws, out);
    } else {
        hipLaunchKernelGGL(fb_kernel, dim3(512), dim3(256), 0, stream, q, k, v, out);
    }
}